// Round 2
// baseline (661.249 us; speedup 1.0000x reference)
//
#include <hip/hip_runtime.h>
#include <hip/hip_bf16.h>

typedef __attribute__((ext_vector_type(8))) short bfrag_t;
typedef __attribute__((ext_vector_type(4))) float facc_t;

#define B_ 4
#define S_ 4096
#define D_ 256

__device__ __forceinline__ short f2bf(float f) {
  union { float fv; unsigned u; } x; x.fv = f;
  unsigned r = x.u + 0x7FFFu + ((x.u >> 16) & 1u);
  return (short)(r >> 16);
}

__device__ __forceinline__ facc_t mfma16(bfrag_t a, bfrag_t b, facc_t c) {
  return __builtin_amdgcn_mfma_f32_16x16x32_bf16(a, b, c, 0, 0, 0);
}

// ---- transpose weights to bf16: WT[p][e][d] = W_p[d][e] --------------------
// grid 48: p = b>>4, e-chunk = b&15
__global__ void wt_kernel(const float* __restrict__ Wq, const float* __restrict__ Wk,
                          const float* __restrict__ Wv, short* __restrict__ WT) {
  const int p = blockIdx.x >> 4;
  const float* W = (p == 0) ? Wq : ((p == 1) ? Wk : Wv);
  short* o = WT + p * (D_ * D_);
  const int e = (blockIdx.x & 15) * 16 + (threadIdx.x >> 4);
  const int td = threadIdx.x & 15;
  #pragma unroll
  for (int dd = 0; dd < 16; ++dd) {
    int d = td * 16 + dd;
    o[e * D_ + d] = f2bf(W[d * D_ + e]);
  }
}

// ---- QKV projection: one projection per block (p = bid>>8) -----------------
__global__ __launch_bounds__(256) void proj_kernel(
    const float* __restrict__ X, const short* __restrict__ WT,
    short* __restrict__ Qb, short* __restrict__ Kb, short* __restrict__ VT) {
  const int tid  = threadIdx.x;
  const int wave = tid >> 6, lane = tid & 63;
  const int lrow = lane & 15, kch = lane >> 4;
  const int p  = blockIdx.x >> 8;
  const int rb = blockIdx.x & 255;
  const int row0 = rb * 64 + wave * 16;           // 16 rows per wave
  const int arow = row0 + lrow;
  const int bblk = row0 >> 12;                    // batch index

  // A-frags: X rows in bf16, k = kt*32 + kch*8 + e  (contiguous 8)
  bfrag_t af[8];
  #pragma unroll
  for (int kt = 0; kt < 8; ++kt) {
    const float* src = X + (size_t)arow * D_ + kt * 32 + kch * 8;
    float4 a = *reinterpret_cast<const float4*>(src);
    float4 b = *reinterpret_cast<const float4*>(src + 4);
    bfrag_t f;
    f[0] = f2bf(a.x); f[1] = f2bf(a.y); f[2] = f2bf(a.z); f[3] = f2bf(a.w);
    f[4] = f2bf(b.x); f[5] = f2bf(b.y); f[6] = f2bf(b.z); f[7] = f2bf(b.w);
    af[kt] = f;
  }

  const short* Wp = WT + p * (D_ * D_);
  facc_t acc[16];
  #pragma unroll
  for (int nt = 0; nt < 16; ++nt) acc[nt] = (facc_t)0.0f;
  #pragma unroll
  for (int kt = 0; kt < 8; ++kt) {
    #pragma unroll
    for (int nt = 0; nt < 16; ++nt) {
      bfrag_t bf = *reinterpret_cast<const bfrag_t*>(
          Wp + (nt * 16 + lrow) * D_ + kt * 32 + kch * 8);
      acc[nt] = mfma16(af[kt], bf, acc[nt]);
    }
  }
  // C/D layout: row = kch*4 + r (local), col = nt*16 + lrow
  if (p == 0) {
    #pragma unroll
    for (int nt = 0; nt < 16; ++nt)
      #pragma unroll
      for (int r = 0; r < 4; ++r)
        Qb[(size_t)(row0 + kch * 4 + r) * D_ + nt * 16 + lrow] =
            f2bf(acc[nt][r] * 0.0625f);   // fold 1/sqrt(256)
  } else if (p == 1) {
    #pragma unroll
    for (int nt = 0; nt < 16; ++nt)
      #pragma unroll
      for (int r = 0; r < 4; ++r)
        Kb[(size_t)(row0 + kch * 4 + r) * D_ + nt * 16 + lrow] = f2bf(acc[nt][r]);
  } else {
    #pragma unroll
    for (int nt = 0; nt < 16; ++nt)
      #pragma unroll
      for (int r = 0; r < 4; ++r) {
        int srow = row0 + kch * 4 + r;
        int d = nt * 16 + lrow;
        VT[((size_t)(bblk * D_ + d)) * S_ + (srow & (S_ - 1))] = f2bf(acc[nt][r]);
      }
  }
}

// ---- flash attention, in-block KV-split x4 ---------------------------------
// block = 4 waves; all waves share one 16-row q-tile; wave w covers
// kv in [w*1024, (w+1)*1024). Online-softmax partials merged via LDS.
__global__ __launch_bounds__(256, 4) void attn_kernel(
    const short* __restrict__ Qb, const short* __restrict__ Kb,
    const short* __restrict__ VT, float* __restrict__ Out) {
  __shared__ __align__(16) short Pl[4][16][72];   // per-wave P buffer
  __shared__ float Mw[4][16], Lw[4][16];
  __shared__ float Ob[16 * 256];                  // combined O accumulator
  const int tid  = threadIdx.x;
  const int wave = tid >> 6, lane = tid & 63;
  const int lrow = lane & 15, kch = lane >> 4;
  // bijective XCD swizzle (nwg=1024): each XCD -> 128 contiguous q-tiles
  const int bid = ((blockIdx.x & 7) << 7) | (blockIdx.x >> 3);
  const int b  = bid >> 8;
  const int qt = bid & 255;
  const int q0 = qt * 16;

  // zero the combine buffer (covered by first __syncthreads below)
  #pragma unroll
  for (int i = 0; i < 16; ++i) Ob[i * 256 + tid] = 0.0f;

  // hoist Q A-frags (all 4 waves read the same 16 rows; L2-hot)
  bfrag_t qf[8];
  #pragma unroll
  for (int kt = 0; kt < 8; ++kt)
    qf[kt] = *reinterpret_cast<const bfrag_t*>(
        Qb + ((size_t)b * S_ + q0 + lrow) * D_ + kt * 32 + kch * 8);

  facc_t oacc[16];
  #pragma unroll
  for (int nt = 0; nt < 16; ++nt) oacc[nt] = (facc_t)0.0f;
  float mrow[4], lsum[4];
  #pragma unroll
  for (int r = 0; r < 4; ++r) { mrow[r] = -3.0e38f; lsum[r] = 0.0f; }

  const short* Kbp = Kb + (size_t)b * S_ * D_;
  const short* Vbp = VT + (size_t)b * D_ * S_;
  const int wbase = wave * 1024;                  // this wave's kv chunk

  #pragma unroll 1
  for (int t = 0; t < 16; ++t) {
    const int kv0 = wbase + t * 64;
    // ---- scores S = Q K^T (pre-scaled via Q) ----
    facc_t sacc[4];
    #pragma unroll
    for (int nt = 0; nt < 4; ++nt) sacc[nt] = (facc_t)0.0f;
    #pragma unroll
    for (int kt = 0; kt < 8; ++kt) {
      #pragma unroll
      for (int nt = 0; nt < 4; ++nt) {
        bfrag_t kf = *reinterpret_cast<const bfrag_t*>(
            Kbp + (size_t)(kv0 + nt * 16 + lrow) * D_ + kt * 32 + kch * 8);
        sacc[nt] = mfma16(qf[kt], kf, sacc[nt]);
      }
    }
    // ---- online softmax (rows r in regs, cols across 16-lane group) ----
    float pv[4][4];
    float sf[4];
    #pragma unroll
    for (int r = 0; r < 4; ++r) {
      float mx = fmaxf(fmaxf(sacc[0][r], sacc[1][r]), fmaxf(sacc[2][r], sacc[3][r]));
      mx = fmaxf(mx, __shfl_xor(mx, 1));
      mx = fmaxf(mx, __shfl_xor(mx, 2));
      mx = fmaxf(mx, __shfl_xor(mx, 4));
      mx = fmaxf(mx, __shfl_xor(mx, 8));
      float mn = fmaxf(mrow[r], mx);
      sf[r] = __expf(mrow[r] - mn);
      mrow[r] = mn;
      float s = 0.0f;
      #pragma unroll
      for (int nt = 0; nt < 4; ++nt) {
        float e = __expf(sacc[nt][r] - mn);
        pv[nt][r] = e;
        s += e;
      }
      s += __shfl_xor(s, 1); s += __shfl_xor(s, 2);
      s += __shfl_xor(s, 4); s += __shfl_xor(s, 8);
      lsum[r] = lsum[r] * sf[r] + s;
    }
    facc_t sfv;
    sfv[0] = sf[0]; sfv[1] = sf[1]; sfv[2] = sf[2]; sfv[3] = sf[3];
    #pragma unroll
    for (int nt = 0; nt < 16; ++nt) oacc[nt] *= sfv;
    // ---- P -> LDS (C-layout write), read back as A-frags ----
    #pragma unroll
    for (int nt = 0; nt < 4; ++nt)
      #pragma unroll
      for (int r = 0; r < 4; ++r)
        Pl[wave][kch * 4 + r][nt * 16 + lrow] = f2bf(pv[nt][r]);
    asm volatile("s_waitcnt lgkmcnt(0)" ::: "memory");
    bfrag_t pf0 = *reinterpret_cast<const bfrag_t*>(&Pl[wave][lrow][kch * 8]);
    bfrag_t pf1 = *reinterpret_cast<const bfrag_t*>(&Pl[wave][lrow][32 + kch * 8]);
    // ---- O += P V  (B-frags contiguous from VT) ----
    #pragma unroll
    for (int nt = 0; nt < 16; ++nt) {
      const short* vrow = Vbp + (size_t)(nt * 16 + lrow) * S_ + kv0 + kch * 8;
      bfrag_t vf0 = *reinterpret_cast<const bfrag_t*>(vrow);
      oacc[nt] = mfma16(pf0, vf0, oacc[nt]);
      bfrag_t vf1 = *reinterpret_cast<const bfrag_t*>(vrow + 32);
      oacc[nt] = mfma16(pf1, vf1, oacc[nt]);
    }
  }

  // ---- cross-wave combine ----
  if (lrow == 0) {
    #pragma unroll
    for (int r = 0; r < 4; ++r) Mw[wave][kch * 4 + r] = mrow[r];
  }
  __syncthreads();
  float f[4];
  #pragma unroll
  for (int r = 0; r < 4; ++r) {
    int rw = kch * 4 + r;
    float mg = fmaxf(fmaxf(Mw[0][rw], Mw[1][rw]), fmaxf(Mw[2][rw], Mw[3][rw]));
    f[r] = __expf(mrow[r] - mg);
    if (lrow == 0) Lw[wave][rw] = lsum[r] * f[r];
  }
  __syncthreads();
  #pragma unroll
  for (int nt = 0; nt < 16; ++nt)
    #pragma unroll
    for (int r = 0; r < 4; ++r)
      atomicAdd(&Ob[(kch * 4 + r) * 256 + nt * 16 + lrow], oacc[nt][r] * f[r]);
  __syncthreads();
  float* Og = Out + ((size_t)b * S_ + q0) * D_;
  #pragma unroll
  for (int i = 0; i < 16; ++i) {
    float lg = Lw[0][i] + Lw[1][i] + Lw[2][i] + Lw[3][i];
    Og[(size_t)i * D_ + tid] = Ob[i * 256 + tid] * (1.0f / lg);
  }
}

extern "C" void kernel_launch(void* const* d_in, const int* in_sizes, int n_in,
                              void* d_out, int out_size, void* d_ws, size_t ws_size,
                              hipStream_t stream) {
  const float* X  = (const float*)d_in[0];
  const float* Wq = (const float*)d_in[1];
  const float* Wk = (const float*)d_in[2];
  const float* Wv = (const float*)d_in[3];
  float* out = (float*)d_out;

  char* ws = (char*)d_ws;
  short* Qb = (short*)(ws);                       // 16384*256 bf16 = 8 MB
  short* Kb = (short*)(ws + 8388608);             // 8 MB
  short* VT = (short*)(ws + 16777216);            // 8 MB (V transposed [B][D][S])
  short* WT = (short*)(ws + 25165824);            // 3*256*256 bf16 = 384 KB

  wt_kernel<<<48, 256, 0, stream>>>(Wq, Wk, Wv, WT);
  proj_kernel<<<768, 256, 0, stream>>>(X, WT, Qb, Kb, VT);
  attn_kernel<<<1024, 256, 0, stream>>>(Qb, Kb, VT, out);
}

// Round 3
// 631.030 us; speedup vs baseline: 1.0479x; 1.0479x over previous
//
#include <hip/hip_runtime.h>
#include <hip/hip_bf16.h>

typedef __attribute__((ext_vector_type(8))) short bfrag_t;
typedef __attribute__((ext_vector_type(4))) float facc_t;

#define B_ 4
#define S_ 4096
#define D_ 256

__device__ __forceinline__ short f2bf(float f) {
  union { float fv; unsigned u; } x; x.fv = f;
  unsigned r = x.u + 0x7FFFu + ((x.u >> 16) & 1u);
  return (short)(r >> 16);
}

__device__ __forceinline__ facc_t mfma16(bfrag_t a, bfrag_t b, facc_t c) {
  return __builtin_amdgcn_mfma_f32_16x16x32_bf16(a, b, c, 0, 0, 0);
}

// ---- transpose weights to bf16: WT[p][e][d] = W_p[d][e] --------------------
__global__ void wt_kernel(const float* __restrict__ Wq, const float* __restrict__ Wk,
                          const float* __restrict__ Wv, short* __restrict__ WT) {
  const int p = blockIdx.x >> 4;
  const float* W = (p == 0) ? Wq : ((p == 1) ? Wk : Wv);
  short* o = WT + p * (D_ * D_);
  const int e = (blockIdx.x & 15) * 16 + (threadIdx.x >> 4);
  const int td = threadIdx.x & 15;
  #pragma unroll
  for (int dd = 0; dd < 16; ++dd) {
    int d = td * 16 + dd;
    o[e * D_ + d] = f2bf(W[d * D_ + e]);
  }
}

// ---- QKV projection: one projection per block (p = bid>>8) -----------------
__global__ __launch_bounds__(256) void proj_kernel(
    const float* __restrict__ X, const short* __restrict__ WT,
    short* __restrict__ Qb, short* __restrict__ Kb, short* __restrict__ VT) {
  const int tid  = threadIdx.x;
  const int wave = tid >> 6, lane = tid & 63;
  const int lrow = lane & 15, kch = lane >> 4;
  const int p  = blockIdx.x >> 8;
  const int rb = blockIdx.x & 255;
  const int row0 = rb * 64 + wave * 16;           // 16 rows per wave
  const int arow = row0 + lrow;
  const int bblk = row0 >> 12;                    // batch index

  bfrag_t af[8];
  #pragma unroll
  for (int kt = 0; kt < 8; ++kt) {
    const float* src = X + (size_t)arow * D_ + kt * 32 + kch * 8;
    float4 a = *reinterpret_cast<const float4*>(src);
    float4 b = *reinterpret_cast<const float4*>(src + 4);
    bfrag_t f;
    f[0] = f2bf(a.x); f[1] = f2bf(a.y); f[2] = f2bf(a.z); f[3] = f2bf(a.w);
    f[4] = f2bf(b.x); f[5] = f2bf(b.y); f[6] = f2bf(b.z); f[7] = f2bf(b.w);
    af[kt] = f;
  }

  const short* Wp = WT + p * (D_ * D_);
  facc_t acc[16];
  #pragma unroll
  for (int nt = 0; nt < 16; ++nt) acc[nt] = (facc_t)0.0f;
  #pragma unroll
  for (int kt = 0; kt < 8; ++kt) {
    #pragma unroll
    for (int nt = 0; nt < 16; ++nt) {
      bfrag_t bf = *reinterpret_cast<const bfrag_t*>(
          Wp + (nt * 16 + lrow) * D_ + kt * 32 + kch * 8);
      acc[nt] = mfma16(af[kt], bf, acc[nt]);
    }
  }
  if (p == 0) {
    #pragma unroll
    for (int nt = 0; nt < 16; ++nt)
      #pragma unroll
      for (int r = 0; r < 4; ++r)
        Qb[(size_t)(row0 + kch * 4 + r) * D_ + nt * 16 + lrow] =
            f2bf(acc[nt][r] * 0.0625f);   // fold 1/sqrt(256)
  } else if (p == 1) {
    #pragma unroll
    for (int nt = 0; nt < 16; ++nt)
      #pragma unroll
      for (int r = 0; r < 4; ++r)
        Kb[(size_t)(row0 + kch * 4 + r) * D_ + nt * 16 + lrow] = f2bf(acc[nt][r]);
  } else {
    #pragma unroll
    for (int nt = 0; nt < 16; ++nt)
      #pragma unroll
      for (int r = 0; r < 4; ++r) {
        int srow = row0 + kch * 4 + r;
        int d = nt * 16 + lrow;
        VT[((size_t)(bblk * D_ + d)) * S_ + (srow & (S_ - 1))] = f2bf(acc[nt][r]);
      }
  }
}

// ---- flash attention, in-block KV-split x4, deterministic tree combine -----
// block = 4 waves; all share one 16-row q-tile; wave w covers kv [w*1024,(w+1)*1024)
__global__ __launch_bounds__(256, 3) void attn_kernel(
    const short* __restrict__ Qb, const short* __restrict__ Kb,
    const short* __restrict__ VT, float* __restrict__ Out) {
  __shared__ __align__(16) short Pl[4][16][72];   // per-wave P buffer (9.2 KB)
  __shared__ float Mw[4][16], Lw[4][16];
  __shared__ __align__(16) float Slab[2][64 * 64]; // 2 x 16 KB reduce slabs
  const int tid  = threadIdx.x;
  const int wave = tid >> 6, lane = tid & 63;
  const int lrow = lane & 15, kch = lane >> 4;
  // bijective XCD swizzle (nwg=1024): each XCD -> 128 contiguous q-tiles
  const int bid = ((blockIdx.x & 7) << 7) | (blockIdx.x >> 3);
  const int b  = bid >> 8;
  const int qt = bid & 255;
  const int q0 = qt * 16;

  // hoist Q A-frags (all 4 waves read the same 16 rows; L2-hot)
  bfrag_t qf[8];
  #pragma unroll
  for (int kt = 0; kt < 8; ++kt)
    qf[kt] = *reinterpret_cast<const bfrag_t*>(
        Qb + ((size_t)b * S_ + q0 + lrow) * D_ + kt * 32 + kch * 8);

  facc_t oacc[16];
  #pragma unroll
  for (int nt = 0; nt < 16; ++nt) oacc[nt] = (facc_t)0.0f;
  float mrow[4], lsum[4];
  #pragma unroll
  for (int r = 0; r < 4; ++r) { mrow[r] = -3.0e38f; lsum[r] = 0.0f; }

  const short* Kbp = Kb + (size_t)b * S_ * D_;
  const short* Vbp = VT + (size_t)b * D_ * S_;
  const int wbase = wave * 1024;                  // this wave's kv chunk

  #pragma unroll 1
  for (int t = 0; t < 16; ++t) {
    const int kv0 = wbase + t * 64;
    // ---- scores S = Q K^T (pre-scaled via Q) ----
    facc_t sacc[4];
    #pragma unroll
    for (int nt = 0; nt < 4; ++nt) sacc[nt] = (facc_t)0.0f;
    #pragma unroll
    for (int kt = 0; kt < 8; ++kt) {
      #pragma unroll
      for (int nt = 0; nt < 4; ++nt) {
        bfrag_t kf = *reinterpret_cast<const bfrag_t*>(
            Kbp + (size_t)(kv0 + nt * 16 + lrow) * D_ + kt * 32 + kch * 8);
        sacc[nt] = mfma16(qf[kt], kf, sacc[nt]);
      }
    }
    // ---- online softmax (rows r in regs, cols across 16-lane group) ----
    float pv[4][4];
    float sf[4];
    #pragma unroll
    for (int r = 0; r < 4; ++r) {
      float mx = fmaxf(fmaxf(sacc[0][r], sacc[1][r]), fmaxf(sacc[2][r], sacc[3][r]));
      mx = fmaxf(mx, __shfl_xor(mx, 1));
      mx = fmaxf(mx, __shfl_xor(mx, 2));
      mx = fmaxf(mx, __shfl_xor(mx, 4));
      mx = fmaxf(mx, __shfl_xor(mx, 8));
      float mn = fmaxf(mrow[r], mx);
      sf[r] = __expf(mrow[r] - mn);
      mrow[r] = mn;
      float s = 0.0f;
      #pragma unroll
      for (int nt = 0; nt < 4; ++nt) {
        float e = __expf(sacc[nt][r] - mn);
        pv[nt][r] = e;
        s += e;
      }
      s += __shfl_xor(s, 1); s += __shfl_xor(s, 2);
      s += __shfl_xor(s, 4); s += __shfl_xor(s, 8);
      lsum[r] = lsum[r] * sf[r] + s;
    }
    facc_t sfv;
    sfv[0] = sf[0]; sfv[1] = sf[1]; sfv[2] = sf[2]; sfv[3] = sf[3];
    #pragma unroll
    for (int nt = 0; nt < 16; ++nt) oacc[nt] *= sfv;
    // ---- P -> LDS (C-layout write), read back as A-frags ----
    #pragma unroll
    for (int nt = 0; nt < 4; ++nt)
      #pragma unroll
      for (int r = 0; r < 4; ++r)
        Pl[wave][kch * 4 + r][nt * 16 + lrow] = f2bf(pv[nt][r]);
    asm volatile("s_waitcnt lgkmcnt(0)" ::: "memory");
    bfrag_t pf0 = *reinterpret_cast<const bfrag_t*>(&Pl[wave][lrow][kch * 8]);
    bfrag_t pf1 = *reinterpret_cast<const bfrag_t*>(&Pl[wave][lrow][32 + kch * 8]);
    // ---- O += P V  (B-frags contiguous from VT) ----
    #pragma unroll
    for (int nt = 0; nt < 16; ++nt) {
      const short* vrow = Vbp + (size_t)(nt * 16 + lrow) * S_ + kv0 + kch * 8;
      bfrag_t vf0 = *reinterpret_cast<const bfrag_t*>(vrow);
      oacc[nt] = mfma16(pf0, vf0, oacc[nt]);
      bfrag_t vf1 = *reinterpret_cast<const bfrag_t*>(vrow + 32);
      oacc[nt] = mfma16(pf1, vf1, oacc[nt]);
    }
  }

  // ---- cross-wave combine: m/l merge then 2-step tree over LDS slabs ----
  if (lrow == 0) {
    #pragma unroll
    for (int r = 0; r < 4; ++r) Mw[wave][kch * 4 + r] = mrow[r];
  }
  __syncthreads();
  float f[4];
  #pragma unroll
  for (int r = 0; r < 4; ++r) {
    int rw = kch * 4 + r;
    float mg = fmaxf(fmaxf(Mw[0][rw], Mw[1][rw]), fmaxf(Mw[2][rw], Mw[3][rw]));
    f[r] = __expf(mrow[r] - mg);
    if (lrow == 0) Lw[wave][rw] = lsum[r] * f[r];
  }
  facc_t fv;
  fv[0] = f[0]; fv[1] = f[1]; fv[2] = f[2]; fv[3] = f[3];
  #pragma unroll
  for (int nt = 0; nt < 16; ++nt) oacc[nt] *= fv;
  // step 1: waves 2,3 publish; waves 0,1 accumulate
  if (wave >= 2) {
    #pragma unroll
    for (int nt = 0; nt < 16; ++nt)
      #pragma unroll
      for (int r = 0; r < 4; ++r)
        Slab[wave - 2][(nt * 4 + r) * 64 + lane] = oacc[nt][r];
  }
  __syncthreads();
  if (wave < 2) {
    #pragma unroll
    for (int nt = 0; nt < 16; ++nt)
      #pragma unroll
      for (int r = 0; r < 4; ++r)
        oacc[nt][r] += Slab[wave][(nt * 4 + r) * 64 + lane];
  }
  __syncthreads();
  // step 2: wave 1 publishes; wave 0 finishes + stores
  if (wave == 1) {
    #pragma unroll
    for (int nt = 0; nt < 16; ++nt)
      #pragma unroll
      for (int r = 0; r < 4; ++r)
        Slab[1][(nt * 4 + r) * 64 + lane] = oacc[nt][r];
  }
  __syncthreads();
  if (wave == 0) {
    float lg[4];
    #pragma unroll
    for (int r = 0; r < 4; ++r) {
      int rw = kch * 4 + r;
      lg[r] = 1.0f / (Lw[0][rw] + Lw[1][rw] + Lw[2][rw] + Lw[3][rw]);
    }
    float* Og = Out + ((size_t)b * S_ + q0) * D_;
    #pragma unroll
    for (int nt = 0; nt < 16; ++nt)
      #pragma unroll
      for (int r = 0; r < 4; ++r)
        Og[(size_t)(kch * 4 + r) * D_ + nt * 16 + lrow] =
            (oacc[nt][r] + Slab[1][(nt * 4 + r) * 64 + lane]) * lg[r];
  }
}

extern "C" void kernel_launch(void* const* d_in, const int* in_sizes, int n_in,
                              void* d_out, int out_size, void* d_ws, size_t ws_size,
                              hipStream_t stream) {
  const float* X  = (const float*)d_in[0];
  const float* Wq = (const float*)d_in[1];
  const float* Wk = (const float*)d_in[2];
  const float* Wv = (const float*)d_in[3];
  float* out = (float*)d_out;

  char* ws = (char*)d_ws;
  short* Qb = (short*)(ws);                       // 8 MB
  short* Kb = (short*)(ws + 8388608);             // 8 MB
  short* VT = (short*)(ws + 16777216);            // 8 MB (V transposed [B][D][S])
  short* WT = (short*)(ws + 25165824);            // 384 KB

  wt_kernel<<<48, 256, 0, stream>>>(Wq, Wk, Wv, WT);
  proj_kernel<<<768, 256, 0, stream>>>(X, WT, Qb, Kb, VT);
  attn_kernel<<<1024, 256, 0, stream>>>(Qb, Kb, VT, out);
}

// Round 4
// 277.055 us; speedup vs baseline: 2.3867x; 2.2776x over previous
//
#include <hip/hip_runtime.h>
#include <hip/hip_bf16.h>

typedef __attribute__((ext_vector_type(8))) short bfrag_t;
typedef __attribute__((ext_vector_type(4))) float facc_t;

#define B_ 4
#define S_ 4096
#define D_ 256

using gas_v = const __attribute__((address_space(1))) void;
using las_v = __attribute__((address_space(3))) void;

__device__ __forceinline__ short f2bf(float f) {
  union { float fv; unsigned u; } x; x.fv = f;
  unsigned r = x.u + 0x7FFFu + ((x.u >> 16) & 1u);
  return (short)(r >> 16);
}

__device__ __forceinline__ facc_t mfma16(bfrag_t a, bfrag_t b, facc_t c) {
  return __builtin_amdgcn_mfma_f32_16x16x32_bf16(a, b, c, 0, 0, 0);
}

// ---- transpose weights to bf16: WT[p][e][d] = W_p[d][e] --------------------
__global__ void wt_kernel(const float* __restrict__ Wq, const float* __restrict__ Wk,
                          const float* __restrict__ Wv, short* __restrict__ WT) {
  const int p = blockIdx.x >> 4;
  const float* W = (p == 0) ? Wq : ((p == 1) ? Wk : Wv);
  short* o = WT + p * (D_ * D_);
  const int e = (blockIdx.x & 15) * 16 + (threadIdx.x >> 4);
  const int td = threadIdx.x & 15;
  #pragma unroll
  for (int dd = 0; dd < 16; ++dd) {
    int d = td * 16 + dd;
    o[e * D_ + d] = f2bf(W[d * D_ + e]);
  }
}

// ---- QKV projection: one projection per block (p = bid>>8) -----------------
__global__ __launch_bounds__(256) void proj_kernel(
    const float* __restrict__ X, const short* __restrict__ WT,
    short* __restrict__ Qb, short* __restrict__ Kb, short* __restrict__ VT) {
  const int tid  = threadIdx.x;
  const int wave = tid >> 6, lane = tid & 63;
  const int lrow = lane & 15, kch = lane >> 4;
  const int p  = blockIdx.x >> 8;
  const int rb = blockIdx.x & 255;
  const int row0 = rb * 64 + wave * 16;
  const int arow = row0 + lrow;
  const int bblk = row0 >> 12;

  bfrag_t af[8];
  #pragma unroll
  for (int kt = 0; kt < 8; ++kt) {
    const float* src = X + (size_t)arow * D_ + kt * 32 + kch * 8;
    float4 a = *reinterpret_cast<const float4*>(src);
    float4 b = *reinterpret_cast<const float4*>(src + 4);
    bfrag_t f;
    f[0] = f2bf(a.x); f[1] = f2bf(a.y); f[2] = f2bf(a.z); f[3] = f2bf(a.w);
    f[4] = f2bf(b.x); f[5] = f2bf(b.y); f[6] = f2bf(b.z); f[7] = f2bf(b.w);
    af[kt] = f;
  }

  const short* Wp = WT + p * (D_ * D_);
  facc_t acc[16];
  #pragma unroll
  for (int nt = 0; nt < 16; ++nt) acc[nt] = (facc_t)0.0f;
  #pragma unroll
  for (int kt = 0; kt < 8; ++kt) {
    #pragma unroll
    for (int nt = 0; nt < 16; ++nt) {
      bfrag_t bf = *reinterpret_cast<const bfrag_t*>(
          Wp + (nt * 16 + lrow) * D_ + kt * 32 + kch * 8);
      acc[nt] = mfma16(af[kt], bf, acc[nt]);
    }
  }
  if (p == 0) {
    #pragma unroll
    for (int nt = 0; nt < 16; ++nt)
      #pragma unroll
      for (int r = 0; r < 4; ++r)
        Qb[(size_t)(row0 + kch * 4 + r) * D_ + nt * 16 + lrow] =
            f2bf(acc[nt][r] * 0.0625f);   // fold 1/sqrt(256)
  } else if (p == 1) {
    #pragma unroll
    for (int nt = 0; nt < 16; ++nt)
      #pragma unroll
      for (int r = 0; r < 4; ++r)
        Kb[(size_t)(row0 + kch * 4 + r) * D_ + nt * 16 + lrow] = f2bf(acc[nt][r]);
  } else {
    #pragma unroll
    for (int nt = 0; nt < 16; ++nt)
      #pragma unroll
      for (int r = 0; r < 4; ++r) {
        int srow = row0 + kch * 4 + r;
        int d = nt * 16 + lrow;
        VT[((size_t)(bblk * D_ + d)) * S_ + (srow & (S_ - 1))] = f2bf(acc[nt][r]);
      }
  }
}

// ---- flash attention: 8 waves x 16 q-rows, LDS-staged K/V, double-buffered -
__global__ __launch_bounds__(512, 2) void attn_kernel(
    const short* __restrict__ Qb, const short* __restrict__ Kb,
    const short* __restrict__ VT, float* __restrict__ Out) {
  // K tile [64 kv][256 d] (512B rows), V tile [256 d][64 kv] (128B rows),
  // both XOR-swizzled: byte ^= (row&7)<<4. Double-buffered: 2*(32+32) KB.
  __shared__ __align__(16) short Kl[2][64 * 256];
  __shared__ __align__(16) short Vl[2][256 * 64];
  __shared__ __align__(16) short Pl[8][16][72];
  const int tid  = threadIdx.x;
  const int wave = tid >> 6, lane = tid & 63;
  const int lrow = lane & 15, kch = lane >> 4;
  // bijective XCD-chunked swizzle (nwg=128): XCD x gets q-tiles [16x,16x+16)
  const int bid = ((blockIdx.x & 7) << 4) | (blockIdx.x >> 3);
  const int b  = bid >> 5;                 // batch (32 q-tiles per batch)
  const int q0 = (bid & 31) * 128 + wave * 16;   // wave's q-rows within batch

  const short* Kbp = Kb + (size_t)b * S_ * D_;
  const short* Vbp = VT + (size_t)b * D_ * S_;

  // hoist Q A-frags
  bfrag_t qf[8];
  #pragma unroll
  for (int kt = 0; kt < 8; ++kt)
    qf[kt] = *reinterpret_cast<const bfrag_t*>(
        Qb + ((size_t)b * S_ + q0 + lrow) * D_ + kt * 32 + kch * 8);

  // stage one 64-kv tile into buffer bf (8 x 16B DMA per thread)
  auto stage = [&](int bf, int kv0) {
    #pragma unroll
    for (int j = 0; j < 4; ++j) {          // K: 32 KB
      int L = j * 8192 + tid * 16;         // linear byte offset in tile
      int row = L >> 9;
      int colb = (L & 511) ^ ((row & 7) << 4);   // inverse-swizzled source
      const short* src = Kbp + (size_t)(kv0 + row) * D_ + (colb >> 1);
      short* dst = &Kl[bf][(j * 8192 + wave * 1024) >> 1];  // wave-uniform base
      __builtin_amdgcn_global_load_lds((gas_v*)src, (las_v*)dst, 16, 0, 0);
    }
    #pragma unroll
    for (int j = 0; j < 4; ++j) {          // V: 32 KB
      int L = j * 8192 + tid * 16;
      int d = L >> 7;
      int colb = (L & 127) ^ ((d & 7) << 4);
      const short* src = Vbp + (size_t)d * S_ + kv0 + (colb >> 1);
      short* dst = &Vl[bf][(j * 8192 + wave * 1024) >> 1];
      __builtin_amdgcn_global_load_lds((gas_v*)src, (las_v*)dst, 16, 0, 0);
    }
  };

  facc_t oacc[16];
  #pragma unroll
  for (int nt = 0; nt < 16; ++nt) oacc[nt] = (facc_t)0.0f;
  float mrow[4], lsum[4];
  #pragma unroll
  for (int r = 0; r < 4; ++r) { mrow[r] = -3.0e38f; lsum[r] = 0.0f; }

  stage(0, 0);
  asm volatile("s_waitcnt vmcnt(0)" ::: "memory");
  __syncthreads();
  int buf = 0;

  #pragma unroll 1
  for (int t = 0; t < 64; ++t) {
    if (t < 63) stage(buf ^ 1, (t + 1) * 64);     // issue-early prefetch
    // ---- scores S = Q K^T (Q pre-scaled) ----
    facc_t sacc[4];
    #pragma unroll
    for (int nt = 0; nt < 4; ++nt) sacc[nt] = (facc_t)0.0f;
    const char* Kbase = (const char*)&Kl[buf][0];
    #pragma unroll
    for (int kt = 0; kt < 8; ++kt) {
      #pragma unroll
      for (int nt = 0; nt < 4; ++nt) {
        int row = nt * 16 + lrow;
        int colb = (kt * 64 + kch * 16) ^ ((row & 7) << 4);
        bfrag_t kf = *reinterpret_cast<const bfrag_t*>(Kbase + row * 512 + colb);
        sacc[nt] = mfma16(qf[kt], kf, sacc[nt]);
      }
    }
    // ---- online softmax ----
    float pv[4][4];
    float sf[4];
    #pragma unroll
    for (int r = 0; r < 4; ++r) {
      float mx = fmaxf(fmaxf(sacc[0][r], sacc[1][r]), fmaxf(sacc[2][r], sacc[3][r]));
      mx = fmaxf(mx, __shfl_xor(mx, 1));
      mx = fmaxf(mx, __shfl_xor(mx, 2));
      mx = fmaxf(mx, __shfl_xor(mx, 4));
      mx = fmaxf(mx, __shfl_xor(mx, 8));
      float mn = fmaxf(mrow[r], mx);
      sf[r] = __expf(mrow[r] - mn);
      mrow[r] = mn;
      float s = 0.0f;
      #pragma unroll
      for (int nt = 0; nt < 4; ++nt) {
        float e = __expf(sacc[nt][r] - mn);
        pv[nt][r] = e;
        s += e;
      }
      s += __shfl_xor(s, 1); s += __shfl_xor(s, 2);
      s += __shfl_xor(s, 4); s += __shfl_xor(s, 8);
      lsum[r] = lsum[r] * sf[r] + s;
    }
    facc_t sfv;
    sfv[0] = sf[0]; sfv[1] = sf[1]; sfv[2] = sf[2]; sfv[3] = sf[3];
    #pragma unroll
    for (int nt = 0; nt < 16; ++nt) oacc[nt] *= sfv;
    // ---- P -> LDS (C-layout write), read back as A-frags ----
    #pragma unroll
    for (int nt = 0; nt < 4; ++nt)
      #pragma unroll
      for (int r = 0; r < 4; ++r)
        Pl[wave][kch * 4 + r][nt * 16 + lrow] = f2bf(pv[nt][r]);
    asm volatile("s_waitcnt lgkmcnt(0)" ::: "memory");
    bfrag_t pf0 = *reinterpret_cast<const bfrag_t*>(&Pl[wave][lrow][kch * 8]);
    bfrag_t pf1 = *reinterpret_cast<const bfrag_t*>(&Pl[wave][lrow][32 + kch * 8]);
    // ---- O += P V ----
    const char* Vbase = (const char*)&Vl[buf][0];
    #pragma unroll
    for (int nt = 0; nt < 16; ++nt) {
      int d = nt * 16 + lrow;
      const char* vb = Vbase + d * 128;
      bfrag_t vf0 = *reinterpret_cast<const bfrag_t*>(vb + ((kch * 16) ^ ((d & 7) << 4)));
      oacc[nt] = mfma16(pf0, vf0, oacc[nt]);
      bfrag_t vf1 = *reinterpret_cast<const bfrag_t*>(vb + ((64 + kch * 16) ^ ((d & 7) << 4)));
      oacc[nt] = mfma16(pf1, vf1, oacc[nt]);
    }
    asm volatile("s_waitcnt vmcnt(0)" ::: "memory");  // prefetch landed
    __syncthreads();
    buf ^= 1;
  }

  // ---- epilogue: normalize and store fp32 ----
  float inv[4];
  #pragma unroll
  for (int r = 0; r < 4; ++r) inv[r] = 1.0f / lsum[r];
  #pragma unroll
  for (int nt = 0; nt < 16; ++nt)
    #pragma unroll
    for (int r = 0; r < 4; ++r)
      Out[((size_t)b * S_ + q0 + kch * 4 + r) * D_ + nt * 16 + lrow] =
          oacc[nt][r] * inv[r];
}

extern "C" void kernel_launch(void* const* d_in, const int* in_sizes, int n_in,
                              void* d_out, int out_size, void* d_ws, size_t ws_size,
                              hipStream_t stream) {
  const float* X  = (const float*)d_in[0];
  const float* Wq = (const float*)d_in[1];
  const float* Wk = (const float*)d_in[2];
  const float* Wv = (const float*)d_in[3];
  float* out = (float*)d_out;

  char* ws = (char*)d_ws;
  short* Qb = (short*)(ws);                       // 8 MB
  short* Kb = (short*)(ws + 8388608);             // 8 MB
  short* VT = (short*)(ws + 16777216);            // 8 MB (V transposed [B][D][S])
  short* WT = (short*)(ws + 25165824);            // 384 KB

  wt_kernel<<<48, 256, 0, stream>>>(Wq, Wk, Wv, WT);
  proj_kernel<<<768, 256, 0, stream>>>(X, WT, Qb, Kb, VT);
  attn_kernel<<<128, 512, 0, stream>>>(Qb, Kb, VT, out);
}